// Round 7
// baseline (241.305 us; speedup 1.0000x reference)
//
#include <hip/hip_runtime.h>

// LNCC DEBUG1: num = (tp_sum - (p_sum/729)*t_sum)^2 + 1e-5, 9^3 box sums, SAME zero pad.
//
// R11: eliminate the pcol stage. Evidence from R6/R7/R9: every intra-structure
// reorder loses because per-wave LDS ops execute in order — merging stages into one
// inter-barrier segment chains their latencies; R8's win is its segment split. So
// instead of reordering, DELETE a stage: the y-blur is computed directly by each
// output thread reading its 9 consecutive rowT[f][gx][gy..gy+8] values (contiguous
// -> ds_read2_b32 merged, ~15 read instrs for 3 fields) and summing. Per plane:
//   loads -> rowsum -> BAR -> ysum+ring+output -> finalize
// ONE barrier + ONE LDS round-trip per plane (was 2+2). Pre-bar segment is
// byte-identical to R8 (the proven part). Post-bar segment contains only reads.
// rowT double-buffered (parity (k+r)&1, SALU-uniform): readers of buf[i&1] drain
// at bar(i+1); writers of buf[i&1] resume after bar(i+1) -> WAR safe.
// rowsum/finalize are unconditional for lactive: cur is zeroed whenever the plane
// is invalid, so rowT carries zeros and ysum needs no validity guard (identical
// values to R8's guarded gather). Output guard (i>=8 && i<Z+8) unchanged.
// LDS 2*RBUF*4 = 34.5 KB; 2 blocks/CU needs VGPR<=64 (R8 was 60 with same live set).

#define N 192
#define RSTRIDE 46                // rowT row stride: 2-way banks (free), even for read2
#define RBUF (3 * 32 * RSTRIDE)   // 4416 floats per buffer
#define FSTRIDE (32 * RSTRIDE)    // 1472 floats per field

// LDS-only barrier: drain LDS ops, then barrier. No vmcnt drain (prefetch stays in flight).
#define LDS_BARRIER() asm volatile("s_waitcnt lgkmcnt(0)\n\ts_barrier" ::: "memory")

__global__ __launch_bounds__(1024, 4)
void lncc_kernel(const float* __restrict__ t_in,
                 const float* __restrict__ p_in,
                 float* __restrict__ out)
{
    // rowT[buf][f][x][ry]: transposed x-blurred row sums, double-buffered
    __shared__ __align__(16) float rowT[2 * RBUF];   // 34.5 KB

    // ---- work assignment: 512 blocks = 72 xy tiles x {8 or 7} z-chunks ----
    const int bid = blockIdx.x;
    int xy, Z, z0;
    if (bid < 64) {                 // tiles 0..7: 8 chunks of Z=24
        xy = bid >> 3;
        Z  = 24;
        z0 = (bid & 7) * 24;
    } else {                        // tiles 8..71: 7 chunks (28,28,28,27,27,27,27)
        const int q  = bid - 64;
        xy = 8 + q / 7;
        const int zi = q % 7;
        if (zi < 3) { Z = 28; z0 = zi * 28; }
        else        { Z = 27; z0 = 84 + (zi - 3) * 27; }
    }
    const int b  = xy / 36;
    const int t6 = xy % 36;
    const int y0 = (t6 / 6) * 32, x0 = (t6 % 6) * 32;
    const int tid = threadIdx.x;

    // ---- L (row-sum) decode: 3 fields x 40 rows x 8 x-quads = 960 slots (15 waves)
    const int  lf   = tid / 320;          // 0=t 1=p 2=tp (wave-uniform: 320=5*64)
    const int  ls   = tid - lf * 320;
    const int  lry  = ls >> 3;            // raw row 0..39
    const int  lxq  = ls & 7;             // x quad 0..7
    const int  lgy  = y0 - 4 + lry;
    const int  lgx0 = x0 - 4 + 4 * lxq;   // 16B-aligned quad base
    const bool lactive = (tid < 960);
    const bool lyok = ((unsigned)lgy < (unsigned)N);

    // ---- G decode: every thread owns output column (gx,gy); reads 9 rowT values/field
    const int gx = tid & 31;
    const int gy = tid >> 5;

    const size_t plane = (size_t)N * N;
    const float* tb = t_in + (size_t)b * N * plane;
    const float* pb = p_in + (size_t)b * N * plane;
    float*       ob = out  + (size_t)b * N * plane
                           + (size_t)(y0 + gy) * N + (x0 + gx);

    // loop-invariant row base pointers (y clamped; loads stay guarded by lactive&&lyok)
    const int lgyc = lyok ? lgy : 0;
    const float* const trow = tb + (size_t)lgyc * N;
    const float* const prow = pb + (size_t)lgyc * N;
    const float* const arow = (lf == 1) ? prow : trow;   // wave-uniform a-source select

    // per-thread LDS base pointers (buffer 0; + rofs at use, SALU-uniform)
    float* const       wpA   = &rowT[(lf * 32 + 4 * lxq) * RSTRIDE + lry];
    const float* const ybase = &rowT[gx * RSTRIDE + gy];

    float ring_t[9], ring_p[9], ring_tp[9];
    float sum_t = 0.f, sum_p = 0.f, sum_tp = 0.f;
    #pragma unroll
    for (int i = 0; i < 9; ++i) { ring_t[i] = 0.f; ring_p[i] = 0.f; ring_tp[i] = 0.f; }

    const float4 z4 = make_float4(0.f, 0.f, 0.f, 0.f);
    float4 cur0 = z4, cur1 = z4, cur2 = z4;     // row-sum-ready 12 floats for plane i

    // ---- prologue: load + finalize plane 0 into cur (one exposed latency) ----
    {
        const int zp0 = z0 - 4;
        float4 fa0 = z4, fa1 = z4, fa2 = z4, fc0 = z4, fc1 = z4, fc2 = z4;
        if (((unsigned)zp0 < (unsigned)N) && lactive && lyok) {
            const float* ar = arow + (size_t)zp0 * plane;
            const float* cr = prow + (size_t)zp0 * plane;
            const int g0 = lgx0, g1 = lgx0 + 4, g2 = lgx0 + 8;
            if ((unsigned)g0 < (unsigned)N) {
                fa0 = *(const float4*)(ar + g0);
                if (lf == 2) fc0 = *(const float4*)(cr + g0);
            }
            if ((unsigned)g1 < (unsigned)N) {
                fa1 = *(const float4*)(ar + g1);
                if (lf == 2) fc1 = *(const float4*)(cr + g1);
            }
            if ((unsigned)g2 < (unsigned)N) {
                fa2 = *(const float4*)(ar + g2);
                if (lf == 2) fc2 = *(const float4*)(cr + g2);
            }
        }
        if (lactive) {
            float4 A0 = fa0, A1 = fa1, A2 = fa2;
            if (lf == 2) {
                A0.x *= fc0.x; A0.y *= fc0.y; A0.z *= fc0.z; A0.w *= fc0.w;
                A1.x *= fc1.x; A1.y *= fc1.y; A1.z *= fc1.z; A1.w *= fc1.w;
                A2.x *= fc2.x; A2.y *= fc2.y; A2.z *= fc2.z; A2.w *= fc2.w;
            }
            cur0 = A0; cur1 = A1; cur2 = A2;
        }
    }

    #pragma unroll 1
    for (int k = 0; k < 4; ++k) {
      #pragma unroll
      for (int r = 0; r < 9; ++r) {
        const int i  = k * 9 + r;
        const int zp = z0 - 4 + i;           // plane i
        const int zn = zp + 1;               // plane i+1
        const bool vn = (i + 1 < Z + 8) && ((unsigned)zn < (unsigned)N);
        const int rofs = ((k + r) & 1) * RBUF;   // parity of i (9 odd): SALU-uniform

        // ---- 1. issue loads for plane i+1 (consumed at step 4) ----
        float4 fa0 = z4, fa1 = z4, fa2 = z4, fc0 = z4, fc1 = z4, fc2 = z4;
        if (vn && lactive && lyok) {
            const float* ar = arow + (size_t)zn * plane;
            const float* cr = prow + (size_t)zn * plane;
            const int g0 = lgx0, g1 = lgx0 + 4, g2 = lgx0 + 8;
            if ((unsigned)g0 < (unsigned)N) {
                fa0 = *(const float4*)(ar + g0);
                if (lf == 2) fc0 = *(const float4*)(cr + g0);
            }
            if ((unsigned)g1 < (unsigned)N) {
                fa1 = *(const float4*)(ar + g1);
                if (lf == 2) fc1 = *(const float4*)(cr + g1);
            }
            if ((unsigned)g2 < (unsigned)N) {
                fa2 = *(const float4*)(ar + g2);
                if (lf == 2) fc2 = *(const float4*)(cr + g2);
            }
        }

        // ---- 2. RowSum(plane i) from cur -> rowT[i&1] (unconditional: zeros flow
        //         for invalid planes, so ysum below needs no guard) ----
        if (lactive) {
            const float v0 = cur0.x, v1 = cur0.y, v2  = cur0.z, v3  = cur0.w;
            const float v4 = cur1.x, v5 = cur1.y, v6  = cur1.z, v7  = cur1.w;
            const float v8 = cur2.x, v9 = cur2.y, v10 = cur2.z, v11 = cur2.w;
            float s0 = ((v0+v1) + (v2+v3)) + ((v4+v5) + (v6+v7)) + v8;
            float s1 = s0 - v0 + v9;
            float s2 = s1 - v1 + v10;
            float s3 = s2 - v2 + v11;
            float* wp = wpA + rofs;
            wp[0]           = s0;
            wp[RSTRIDE]     = s1;
            wp[2 * RSTRIDE] = s2;
            wp[3 * RSTRIDE] = s3;
        }
        LDS_BARRIER();   // seals rowT[i&1]; also drains prev iter's ysum reads (WAR)

        // ---- 3. YSum+Gather(plane i): 9 consecutive rowT values per field ----
        {
            const float* a = ybase + rofs;
            const float Pt  = ((a[0]+a[1]) + (a[2]+a[3]))
                            + ((a[4]+a[5]) + (a[6]+a[7])) + a[8];
            const float* p2 = a + FSTRIDE;
            const float Pp  = ((p2[0]+p2[1]) + (p2[2]+p2[3]))
                            + ((p2[4]+p2[5]) + (p2[6]+p2[7])) + p2[8];
            const float* q2 = a + 2 * FSTRIDE;
            const float Ptp = ((q2[0]+q2[1]) + (q2[2]+q2[3]))
                            + ((q2[4]+q2[5]) + (q2[6]+q2[7])) + q2[8];
            sum_t  += Pt  - ring_t[r];  ring_t[r]  = Pt;
            sum_p  += Pp  - ring_p[r];  ring_p[r]  = Pp;
            sum_tp += Ptp - ring_tp[r]; ring_tp[r] = Ptp;
        }
        if (i >= 8 && i < Z + 8) {
            const float cross = sum_tp - (sum_p * (1.0f / 729.0f)) * sum_t;
            ob[(size_t)(z0 + i - 8) * plane] = cross * cross + 1e-5f;
        }

        // ---- 4. finalize: cur = (lf==2 ? a*c : a); zeros when plane invalid ----
        if (lactive) {
            float4 A0 = fa0, A1 = fa1, A2 = fa2;
            if (lf == 2) {
                A0.x *= fc0.x; A0.y *= fc0.y; A0.z *= fc0.z; A0.w *= fc0.w;
                A1.x *= fc1.x; A1.y *= fc1.y; A1.z *= fc1.z; A1.w *= fc1.w;
                A2.x *= fc2.x; A2.y *= fc2.y; A2.z *= fc2.z; A2.w *= fc2.w;
            }
            cur0 = A0; cur1 = A1; cur2 = A2;
        }
      }
    }
}

extern "C" void kernel_launch(void* const* d_in, const int* in_sizes, int n_in,
                              void* d_out, int out_size, void* d_ws, size_t ws_size,
                              hipStream_t stream) {
    const float* y_true = (const float*)d_in[0];
    const float* y_pred = (const float*)d_in[1];
    float* out = (float*)d_out;
    dim3 grid(512);
    dim3 block(1024);
    hipLaunchKernelGGL(lncc_kernel, grid, block, 0, stream, y_true, y_pred, out);
}

// Round 8
// 210.982 us; speedup vs baseline: 1.1437x; 1.1437x over previous
//
#include <hip/hip_runtime.h>

// LNCC DEBUG1: num = (tp_sum - (p_sum/729)*t_sum)^2 + 1e-5, 9^3 box sums, SAME zero pad.
//
// R12 = R8 champion (110 us) with ONE change: colsum widened to 8 outputs/thread.
// Counter-derived model: the LDS pipe is the dominant busy resource (~1530-1770
// issue-cycles per block-plane ~= 46-53 us of the 110 us wall across 36 planes x
// 2 blocks/CU); colsum's 72 b64-read instrs/block-plane is the biggest term.
// R11 (pcol deleted, direct ysum) proved factoring matters: 3x read words + 18M
// bank-conflict cycles = +30 us. So keep the pcol factoring and make it MORE
// factored: 3 fields x 4 y-octets x 32 x = 384 threads (6 waves), each reading 16
// consecutive rowsum values (8x float2, same alignment, same 2-way-free banks) and
// sliding out 8 outputs -> reads/output 3->2, colsum read instrs 72->48, burst
// pressure halved. Rowsum, barriers, gather, prefetch: byte-identical to R8.

#define N 192
#define RSTRIDE 46   // rowT stride: 2-way banks (free) + 8B-aligned float2 reads

// LDS-only barrier: drain LDS ops, then barrier. No vmcnt drain (prefetch stays in flight).
#define LDS_BARRIER() asm volatile("s_waitcnt lgkmcnt(0)\n\ts_barrier" ::: "memory")

__global__ __launch_bounds__(1024, 4)
void lncc_kernel(const float* __restrict__ t_in,
                 const float* __restrict__ p_in,
                 float* __restrict__ out)
{
    // rowT[f][x][ry]: transposed x-blurred row sums (single-buffered)
    __shared__ __align__(16) float rowT[3 * 32 * RSTRIDE];   // 17.3 KB
    // pcol[f][y][x]: per-plane 2D (9x9) box sums
    __shared__ float pcol[3 * 32 * 32];                      // 12 KB

    // ---- work assignment: 512 blocks = 72 xy tiles x {8 or 7} z-chunks ----
    const int bid = blockIdx.x;
    int xy, Z, z0;
    if (bid < 64) {                 // tiles 0..7: 8 chunks of Z=24
        xy = bid >> 3;
        Z  = 24;
        z0 = (bid & 7) * 24;
    } else {                        // tiles 8..71: 7 chunks (28,28,28,27,27,27,27)
        const int q  = bid - 64;
        xy = 8 + q / 7;
        const int zi = q % 7;
        if (zi < 3) { Z = 28; z0 = zi * 28; }
        else        { Z = 27; z0 = 84 + (zi - 3) * 27; }
    }
    const int b  = xy / 36;
    const int t6 = xy % 36;
    const int y0 = (t6 / 6) * 32, x0 = (t6 % 6) * 32;
    const int tid = threadIdx.x;

    // ---- L (row-sum) decode: 3 fields x 40 rows x 8 x-quads = 960 slots (15 waves)
    const int  lf   = tid / 320;          // 0=t 1=p 2=tp (wave-uniform: 320=5*64)
    const int  ls   = tid - lf * 320;
    const int  lry  = ls >> 3;            // raw row 0..39
    const int  lxq  = ls & 7;             // x quad 0..7
    const int  lgy  = y0 - 4 + lry;
    const int  lgx0 = x0 - 4 + 4 * lxq;   // 16B-aligned quad base
    const bool lactive = (tid < 960);
    const bool lyok = ((unsigned)lgy < (unsigned)N);

    // ---- C (col-sum) decode: 3 fields x 4 y-octets x 32 x = 384 slots (6 waves)
    const int  cf  = tid >> 7;            // field 0..2 (wave-uniform: 128 = 2 waves)
    const int  cyq = (tid >> 5) & 3;      // y-octet 0..3
    const int  cx  = tid & 31;
    const bool cactive = (tid < 384);

    // ---- G decode: thread owns output column (gx,gy)
    const int gx = tid & 31;
    const int gy = tid >> 5;

    const size_t plane = (size_t)N * N;
    const float* tb = t_in + (size_t)b * N * plane;
    const float* pb = p_in + (size_t)b * N * plane;
    float*       ob = out  + (size_t)b * N * plane
                           + (size_t)(y0 + gy) * N + (x0 + gx);

    // loop-invariant row base pointers (y clamped; loads stay guarded by lactive&&lyok)
    const int lgyc = lyok ? lgy : 0;
    const float* const trow = tb + (size_t)lgyc * N;
    const float* const prow = pb + (size_t)lgyc * N;
    const float* const arow = (lf == 1) ? prow : trow;   // wave-uniform a-source select

    float ring_t[9], ring_p[9], ring_tp[9];
    float sum_t = 0.f, sum_p = 0.f, sum_tp = 0.f;
    #pragma unroll
    for (int i = 0; i < 9; ++i) { ring_t[i] = 0.f; ring_p[i] = 0.f; ring_tp[i] = 0.f; }

    const float4 z4 = make_float4(0.f, 0.f, 0.f, 0.f);
    float4 cur0 = z4, cur1 = z4, cur2 = z4;     // row-sum-ready 12 floats for plane i

    // ---- prologue: load + finalize plane 0 (one exposed latency per block)
    {
        const int zp0 = z0 - 4;
        if (((unsigned)zp0 < (unsigned)N) && lactive && lyok) {
            const float* ar = arow + (size_t)zp0 * plane;
            const float* cr = prow + (size_t)zp0 * plane;
            float4 a[3], c[3];
            #pragma unroll
            for (int q = 0; q < 3; ++q) {
                a[q] = z4; c[q] = z4;
                const int gxq = lgx0 + 4 * q;
                if ((unsigned)gxq < (unsigned)N) {
                    a[q] = *(const float4*)(ar + gxq);
                    if (lf == 2) c[q] = *(const float4*)(cr + gxq);
                }
            }
            if (lf == 2) {
                #pragma unroll
                for (int q = 0; q < 3; ++q) {
                    a[q].x *= c[q].x; a[q].y *= c[q].y;
                    a[q].z *= c[q].z; a[q].w *= c[q].w;
                }
            }
            cur0 = a[0]; cur1 = a[1]; cur2 = a[2];
        }
    }

    #pragma unroll 1
    for (int k = 0; k < 4; ++k) {
      #pragma unroll
      for (int r = 0; r < 9; ++r) {
        const int i  = k * 9 + r;
        const int zp = z0 - 4 + i;           // plane i
        const int zn = zp + 1;               // plane i+1
        const bool vi = (i < Z + 8)     && ((unsigned)zp < (unsigned)N);
        const bool vn = (i + 1 < Z + 8) && ((unsigned)zn < (unsigned)N);

        // ---- 1. issue loads for plane i+1 (consumed at step 5) ----
        float4 fa0 = z4, fa1 = z4, fa2 = z4, fc0 = z4, fc1 = z4, fc2 = z4;
        if (vn && lactive && lyok) {
            const float* ar = arow + (size_t)zn * plane;
            const float* cr = prow + (size_t)zn * plane;
            const int g0 = lgx0, g1 = lgx0 + 4, g2 = lgx0 + 8;
            if ((unsigned)g0 < (unsigned)N) {
                fa0 = *(const float4*)(ar + g0);
                if (lf == 2) fc0 = *(const float4*)(cr + g0);
            }
            if ((unsigned)g1 < (unsigned)N) {
                fa1 = *(const float4*)(ar + g1);
                if (lf == 2) fc1 = *(const float4*)(cr + g1);
            }
            if ((unsigned)g2 < (unsigned)N) {
                fa2 = *(const float4*)(ar + g2);
                if (lf == 2) fc2 = *(const float4*)(cr + g2);
            }
        }

        // ---- 2. RowSum(plane i) from cur -> rowT ----
        if (vi && lactive) {
            const float v0 = cur0.x, v1 = cur0.y, v2  = cur0.z, v3  = cur0.w;
            const float v4 = cur1.x, v5 = cur1.y, v6  = cur1.z, v7  = cur1.w;
            const float v8 = cur2.x, v9 = cur2.y, v10 = cur2.z, v11 = cur2.w;
            float s0 = ((v0+v1) + (v2+v3)) + ((v4+v5) + (v6+v7)) + v8;
            float s1 = s0 - v0 + v9;
            float s2 = s1 - v1 + v10;
            float s3 = s2 - v2 + v11;
            float* wp = &rowT[(lf * 32 + 4 * lxq) * RSTRIDE + lry];
            wp[0]           = s0;
            wp[RSTRIDE]     = s1;
            wp[2 * RSTRIDE] = s2;
            wp[3 * RSTRIDE] = s3;
        }
        LDS_BARRIER();

        // ---- 3. ColSum(plane i): rowT -> pcol, 8 outputs/thread ----
        if (vi && cactive) {
            const float* rb = &rowT[(cf * 32 + cx) * RSTRIDE + 8 * cyq];
            const float2 u0 = *(const float2*)(rb + 0);
            const float2 u1 = *(const float2*)(rb + 2);
            const float2 u2 = *(const float2*)(rb + 4);
            const float2 u3 = *(const float2*)(rb + 6);
            const float2 u4 = *(const float2*)(rb + 8);
            const float2 u5 = *(const float2*)(rb + 10);
            const float2 u6 = *(const float2*)(rb + 12);
            const float2 u7 = *(const float2*)(rb + 14);
            const float w0 =u0.x, w1 =u0.y, w2 =u1.x, w3 =u1.y;
            const float w4 =u2.x, w5 =u2.y, w6 =u3.x, w7 =u3.y;
            const float w8 =u4.x, w9 =u4.y, w10=u5.x, w11=u5.y;
            const float w12=u6.x, w13=u6.y, w14=u7.x, w15=u7.y;
            float c0 = ((w0+w1)+(w2+w3)) + ((w4+w5)+(w6+w7)) + w8;
            float c1 = c0 - w0 + w9;
            float c2 = c1 - w1 + w10;
            float c3 = c2 - w2 + w11;
            float c4 = c3 - w3 + w12;
            float c5 = c4 - w4 + w13;
            float c6 = c5 - w5 + w14;
            float c7 = c6 - w6 + w15;
            float* pc = &pcol[cf * 1024 + (8 * cyq) * 32 + cx];
            pc[0]   = c0;
            pc[32]  = c1;
            pc[64]  = c2;
            pc[96]  = c3;
            pc[128] = c4;
            pc[160] = c5;
            pc[192] = c6;
            pc[224] = c7;
        }
        LDS_BARRIER();

        // ---- 4. Gather(plane i), z-ring (slot r == i%9), output ----
        float Pt = 0.f, Pp = 0.f, Ptp = 0.f;
        if (vi) {
            Pt  = pcol[       gy * 32 + gx];
            Pp  = pcol[1024 + gy * 32 + gx];
            Ptp = pcol[2048 + gy * 32 + gx];
        }
        sum_t  += Pt  - ring_t[r];  ring_t[r]  = Pt;
        sum_p  += Pp  - ring_p[r];  ring_p[r]  = Pp;
        sum_tp += Ptp - ring_tp[r]; ring_tp[r] = Ptp;
        if (i >= 8 && i < Z + 8) {
            const float cross = sum_tp - (sum_p * (1.0f / 729.0f)) * sum_t;
            ob[(size_t)(z0 + i - 8) * plane] = cross * cross + 1e-5f;
        }

        // ---- 5. finalize: cur = (lf==2 ? a*c : a)  (loads have landed by now) ----
        if (vn && lactive) {
            float4 A0 = fa0, A1 = fa1, A2 = fa2;
            if (lf == 2) {
                A0.x *= fc0.x; A0.y *= fc0.y; A0.z *= fc0.z; A0.w *= fc0.w;
                A1.x *= fc1.x; A1.y *= fc1.y; A1.z *= fc1.z; A1.w *= fc1.w;
                A2.x *= fc2.x; A2.y *= fc2.y; A2.z *= fc2.z; A2.w *= fc2.w;
            }
            cur0 = A0; cur1 = A1; cur2 = A2;
        }
      }
    }
}

extern "C" void kernel_launch(void* const* d_in, const int* in_sizes, int n_in,
                              void* d_out, int out_size, void* d_ws, size_t ws_size,
                              hipStream_t stream) {
    const float* y_true = (const float*)d_in[0];
    const float* y_pred = (const float*)d_in[1];
    float* out = (float*)d_out;
    dim3 grid(512);
    dim3 block(1024);
    hipLaunchKernelGGL(lncc_kernel, grid, block, 0, stream, y_true, y_pred, out);
}

// Round 9
// 209.686 us; speedup vs baseline: 1.1508x; 1.0062x over previous
//
#include <hip/hip_runtime.h>

// LNCC DEBUG1: num = (tp_sum - (p_sum/729)*t_sum)^2 + 1e-5, 9^3 box sums, SAME zero pad.
//
// R13 = R8 champion VERBATIM (110 us, VGPR 60, original 768-thread colsum) plus
// s_setprio phase arbitration. Ledger: barrier count not the cost (R6), pre-bar
// segment length is (R7/R9), LDS factoring matters (R11), LDS instr count at the
// margin doesn't (R12 flat), VALU count at the margin doesn't (R9). Remaining
// model: barrier-convoy phase latency, hidden only by the sibling block on the
// same CU (occupancy 42% vs 82% when fully resident => partial overlap, idle
// issue slots during critical phases). T5 regime: phase-diverse waves on one CU.
// setprio(1) covers the critical skeleton (load-issue -> rowsum -> bar1 -> colsum
// -> bar2); setprio(0) covers the shadow (gather + finalize). Cross-block: the
// block in its critical phase outranks the block in its shadow phase.
// Everything else byte-identical to R8 (60-VGPR version, 4 regs below the
// 2-blocks/CU cliff at 64).

#define N 192
#define RSTRIDE 46   // rowT stride: 2-way banks (free) + 8B-aligned float2 reads

// LDS-only barrier: drain LDS ops, then barrier. No vmcnt drain (prefetch stays in flight).
#define LDS_BARRIER() asm volatile("s_waitcnt lgkmcnt(0)\n\ts_barrier" ::: "memory")

__global__ __launch_bounds__(1024, 4)
void lncc_kernel(const float* __restrict__ t_in,
                 const float* __restrict__ p_in,
                 float* __restrict__ out)
{
    // rowT[f][x][ry]: transposed x-blurred row sums (single-buffered)
    __shared__ __align__(16) float rowT[3 * 32 * RSTRIDE];   // 17.3 KB
    // pcol[f][y][x]: per-plane 2D (9x9) box sums
    __shared__ float pcol[3 * 32 * 32];                      // 12 KB

    // ---- work assignment: 512 blocks = 72 xy tiles x {8 or 7} z-chunks ----
    const int bid = blockIdx.x;
    int xy, Z, z0;
    if (bid < 64) {                 // tiles 0..7: 8 chunks of Z=24
        xy = bid >> 3;
        Z  = 24;
        z0 = (bid & 7) * 24;
    } else {                        // tiles 8..71: 7 chunks (28,28,28,27,27,27,27)
        const int q  = bid - 64;
        xy = 8 + q / 7;
        const int zi = q % 7;
        if (zi < 3) { Z = 28; z0 = zi * 28; }
        else        { Z = 27; z0 = 84 + (zi - 3) * 27; }
    }
    const int b  = xy / 36;
    const int t6 = xy % 36;
    const int y0 = (t6 / 6) * 32, x0 = (t6 % 6) * 32;
    const int tid = threadIdx.x;

    // ---- L (row-sum) decode: 3 fields x 40 rows x 8 x-quads = 960 slots (15 waves)
    const int  lf   = tid / 320;          // 0=t 1=p 2=tp (wave-uniform: 320=5*64)
    const int  ls   = tid - lf * 320;
    const int  lry  = ls >> 3;            // raw row 0..39
    const int  lxq  = ls & 7;             // x quad 0..7
    const int  lgy  = y0 - 4 + lry;
    const int  lgx0 = x0 - 4 + 4 * lxq;   // 16B-aligned quad base
    const bool lactive = (tid < 960);
    const bool lyok = ((unsigned)lgy < (unsigned)N);

    // ---- C (col-sum) decode: 3 fields x 8 y-quads x 32 x = 768 slots (12 waves)
    const int  cf  = tid >> 8;
    const int  cyq = (tid >> 5) & 7;
    const int  cx  = tid & 31;
    const bool cactive = (tid < 768);

    // ---- G decode: thread owns output column (gx,gy)
    const int gx = tid & 31;
    const int gy = tid >> 5;

    const size_t plane = (size_t)N * N;
    const float* tb = t_in + (size_t)b * N * plane;
    const float* pb = p_in + (size_t)b * N * plane;
    float*       ob = out  + (size_t)b * N * plane
                           + (size_t)(y0 + gy) * N + (x0 + gx);

    // loop-invariant row base pointers (y clamped; loads stay guarded by lactive&&lyok)
    const int lgyc = lyok ? lgy : 0;
    const float* const trow = tb + (size_t)lgyc * N;
    const float* const prow = pb + (size_t)lgyc * N;
    const float* const arow = (lf == 1) ? prow : trow;   // wave-uniform a-source select

    float ring_t[9], ring_p[9], ring_tp[9];
    float sum_t = 0.f, sum_p = 0.f, sum_tp = 0.f;
    #pragma unroll
    for (int i = 0; i < 9; ++i) { ring_t[i] = 0.f; ring_p[i] = 0.f; ring_tp[i] = 0.f; }

    const float4 z4 = make_float4(0.f, 0.f, 0.f, 0.f);
    float4 cur0 = z4, cur1 = z4, cur2 = z4;     // row-sum-ready 12 floats for plane i

    // ---- prologue: load + finalize plane 0 (one exposed latency per block)
    {
        const int zp0 = z0 - 4;
        if (((unsigned)zp0 < (unsigned)N) && lactive && lyok) {
            const float* ar = arow + (size_t)zp0 * plane;
            const float* cr = prow + (size_t)zp0 * plane;
            float4 a[3], c[3];
            #pragma unroll
            for (int q = 0; q < 3; ++q) {
                a[q] = z4; c[q] = z4;
                const int gxq = lgx0 + 4 * q;
                if ((unsigned)gxq < (unsigned)N) {
                    a[q] = *(const float4*)(ar + gxq);
                    if (lf == 2) c[q] = *(const float4*)(cr + gxq);
                }
            }
            if (lf == 2) {
                #pragma unroll
                for (int q = 0; q < 3; ++q) {
                    a[q].x *= c[q].x; a[q].y *= c[q].y;
                    a[q].z *= c[q].z; a[q].w *= c[q].w;
                }
            }
            cur0 = a[0]; cur1 = a[1]; cur2 = a[2];
        }
    }

    #pragma unroll 1
    for (int k = 0; k < 4; ++k) {
      #pragma unroll
      for (int r = 0; r < 9; ++r) {
        const int i  = k * 9 + r;
        const int zp = z0 - 4 + i;           // plane i
        const int zn = zp + 1;               // plane i+1
        const bool vi = (i < Z + 8)     && ((unsigned)zp < (unsigned)N);
        const bool vn = (i + 1 < Z + 8) && ((unsigned)zn < (unsigned)N);

        // critical skeleton begins: load-issue -> rowsum -> bar1 -> colsum -> bar2
        __builtin_amdgcn_s_setprio(1);

        // ---- 1. issue loads for plane i+1 (consumed at step 5) ----
        float4 fa0 = z4, fa1 = z4, fa2 = z4, fc0 = z4, fc1 = z4, fc2 = z4;
        if (vn && lactive && lyok) {
            const float* ar = arow + (size_t)zn * plane;
            const float* cr = prow + (size_t)zn * plane;
            const int g0 = lgx0, g1 = lgx0 + 4, g2 = lgx0 + 8;
            if ((unsigned)g0 < (unsigned)N) {
                fa0 = *(const float4*)(ar + g0);
                if (lf == 2) fc0 = *(const float4*)(cr + g0);
            }
            if ((unsigned)g1 < (unsigned)N) {
                fa1 = *(const float4*)(ar + g1);
                if (lf == 2) fc1 = *(const float4*)(cr + g1);
            }
            if ((unsigned)g2 < (unsigned)N) {
                fa2 = *(const float4*)(ar + g2);
                if (lf == 2) fc2 = *(const float4*)(cr + g2);
            }
        }

        // ---- 2. RowSum(plane i) from cur -> rowT ----
        if (vi && lactive) {
            const float v0 = cur0.x, v1 = cur0.y, v2  = cur0.z, v3  = cur0.w;
            const float v4 = cur1.x, v5 = cur1.y, v6  = cur1.z, v7  = cur1.w;
            const float v8 = cur2.x, v9 = cur2.y, v10 = cur2.z, v11 = cur2.w;
            float s0 = ((v0+v1) + (v2+v3)) + ((v4+v5) + (v6+v7)) + v8;
            float s1 = s0 - v0 + v9;
            float s2 = s1 - v1 + v10;
            float s3 = s2 - v2 + v11;
            float* wp = &rowT[(lf * 32 + 4 * lxq) * RSTRIDE + lry];
            wp[0]           = s0;
            wp[RSTRIDE]     = s1;
            wp[2 * RSTRIDE] = s2;
            wp[3 * RSTRIDE] = s3;
        }
        LDS_BARRIER();

        // ---- 3. ColSum(plane i): rowT -> pcol ----
        if (vi && cactive) {
            const float* rb = &rowT[(cf * 32 + cx) * RSTRIDE + 4 * cyq];
            const float2 u0 = *(const float2*)(rb + 0);
            const float2 u1 = *(const float2*)(rb + 2);
            const float2 u2 = *(const float2*)(rb + 4);
            const float2 u3 = *(const float2*)(rb + 6);
            const float2 u4 = *(const float2*)(rb + 8);
            const float2 u5 = *(const float2*)(rb + 10);
            const float w0=u0.x, w1=u0.y, w2=u1.x,  w3=u1.y;
            const float w4=u2.x, w5=u2.y, w6=u3.x,  w7=u3.y;
            const float w8=u4.x, w9=u4.y, w10=u5.x, w11=u5.y;
            float c0 = ((w0+w1)+(w2+w3)) + ((w4+w5)+(w6+w7)) + w8;
            float c1 = c0 - w0 + w9;
            float c2 = c1 - w1 + w10;
            float c3 = c2 - w2 + w11;
            float* pc = &pcol[cf * 1024 + (4 * cyq) * 32 + cx];
            pc[0]  = c0;
            pc[32] = c1;
            pc[64] = c2;
            pc[96] = c3;
        }
        LDS_BARRIER();

        // shadow phase: gather + finalize (covered by the sibling block's critical phase)
        __builtin_amdgcn_s_setprio(0);

        // ---- 4. Gather(plane i), z-ring (slot r == i%9), output ----
        float Pt = 0.f, Pp = 0.f, Ptp = 0.f;
        if (vi) {
            Pt  = pcol[       gy * 32 + gx];
            Pp  = pcol[1024 + gy * 32 + gx];
            Ptp = pcol[2048 + gy * 32 + gx];
        }
        sum_t  += Pt  - ring_t[r];  ring_t[r]  = Pt;
        sum_p  += Pp  - ring_p[r];  ring_p[r]  = Pp;
        sum_tp += Ptp - ring_tp[r]; ring_tp[r] = Ptp;
        if (i >= 8 && i < Z + 8) {
            const float cross = sum_tp - (sum_p * (1.0f / 729.0f)) * sum_t;
            ob[(size_t)(z0 + i - 8) * plane] = cross * cross + 1e-5f;
        }

        // ---- 5. finalize: cur = (lf==2 ? a*c : a)  (loads have landed by now) ----
        if (vn && lactive) {
            float4 A0 = fa0, A1 = fa1, A2 = fa2;
            if (lf == 2) {
                A0.x *= fc0.x; A0.y *= fc0.y; A0.z *= fc0.z; A0.w *= fc0.w;
                A1.x *= fc1.x; A1.y *= fc1.y; A1.z *= fc1.z; A1.w *= fc1.w;
                A2.x *= fc2.x; A2.y *= fc2.y; A2.z *= fc2.z; A2.w *= fc2.w;
            }
            cur0 = A0; cur1 = A1; cur2 = A2;
        }
      }
    }
}

extern "C" void kernel_launch(void* const* d_in, const int* in_sizes, int n_in,
                              void* d_out, int out_size, void* d_ws, size_t ws_size,
                              hipStream_t stream) {
    const float* y_true = (const float*)d_in[0];
    const float* y_pred = (const float*)d_in[1];
    float* out = (float*)d_out;
    dim3 grid(512);
    dim3 block(1024);
    hipLaunchKernelGGL(lncc_kernel, grid, block, 0, stream, y_true, y_pred, out);
}